// Round 1
// baseline (669.842 us; speedup 1.0000x reference)
//
#include <hip/hip_runtime.h>

typedef __bf16 bf16x8 __attribute__((ext_vector_type(8)));
typedef __bf16 bf16x4 __attribute__((ext_vector_type(4)));
typedef float  f32x4  __attribute__((ext_vector_type(4)));

#define MFMA16(a, b, c) __builtin_amdgcn_mfma_f32_16x16x32_bf16(a, b, c, 0, 0, 0)
#define AS1(p) ((__attribute__((address_space(1))) void*)(p))
#define AS3(p) ((__attribute__((address_space(3))) void*)(p))

// ---------------- fp32 -> bf16 convert (vectorized) ----------------
__global__ __launch_bounds__(256) void cvt_kernel(const float* __restrict__ in,
                                                  __bf16* __restrict__ out, int n4) {
  int i = blockIdx.x * blockDim.x + threadIdx.x;
  if (i < n4) {
    float4 v = ((const float4*)in)[i];
    bf16x4 o = {(__bf16)v.x, (__bf16)v.y, (__bf16)v.z, (__bf16)v.w};
    *(bf16x4*)(out + (size_t)i * 4) = o;
  }
}

// ---------------- weight transpose+convert: fp32 [1024][1024] -> bf16 [N][K] ----
__global__ void wtrans_kernel(const float* __restrict__ in, __bf16* __restrict__ out) {
  __shared__ __bf16 t[64][65];
  int bx = blockIdx.x * 64, by = blockIdx.y * 64;
  int tx = threadIdx.x;
  for (int ty = threadIdx.y; ty < 64; ty += 4)
    t[ty][tx] = (__bf16)in[(size_t)(by + ty) * 1024 + bx + tx];
  __syncthreads();
  for (int ty = threadIdx.y; ty < 64; ty += 4)
    out[(size_t)(bx + ty) * 1024 + by + tx] = t[tx][ty];
}

// ---------------- bf16 GEMM: C[M,N] = A[M,K] @ BT[N,K]^T ----------------
// EPI=0: write bf16 C.  EPI=1: write fp32 C + fp32 residual.
template <int EPI>
__global__ __launch_bounds__(256) void gemm128_kernel(
    const __bf16* __restrict__ A, const __bf16* __restrict__ BT,
    __bf16* __restrict__ Cb, float* __restrict__ Cf,
    const float* __restrict__ resid, int M, int N, int K) {
  __shared__ __bf16 As[128 * 32];
  __shared__ __bf16 Bs[128 * 32];
  const int t = threadIdx.x, l = t & 63, w = t >> 6;
  const int lr = l & 15, lg = l >> 4;
  const int brow = blockIdx.y * 128, bcol = blockIdx.x * 128;
  const int wr = w >> 1, wc = w & 1;
  f32x4 acc[4][4] = {};

  const int srow = w * 16 + (l >> 2);
  const int scol = (l & 3) * 8;
  const __bf16* Ag = A + (size_t)(brow + srow) * K + scol;
  const __bf16* Bg = BT + (size_t)(bcol + srow) * K + scol;
  __bf16* Asw = As + w * 512;
  __bf16* Bsw = Bs + w * 512;

  for (int k0 = 0; k0 < K; k0 += 32) {
    __builtin_amdgcn_global_load_lds(AS1(Ag + k0), AS3(Asw), 16, 0, 0);
    __builtin_amdgcn_global_load_lds(AS1(Ag + k0 + (size_t)64 * K), AS3(Asw + 2048), 16, 0, 0);
    __builtin_amdgcn_global_load_lds(AS1(Bg + k0), AS3(Bsw), 16, 0, 0);
    __builtin_amdgcn_global_load_lds(AS1(Bg + k0 + (size_t)64 * K), AS3(Bsw + 2048), 16, 0, 0);
    __syncthreads();
    bf16x8 a[4], b[4];
#pragma unroll
    for (int m = 0; m < 4; ++m)
      a[m] = *(const bf16x8*)(As + (wr * 64 + m * 16 + lr) * 32 + lg * 8);
#pragma unroll
    for (int n = 0; n < 4; ++n)
      b[n] = *(const bf16x8*)(Bs + (wc * 64 + n * 16 + lr) * 32 + lg * 8);
#pragma unroll
    for (int m = 0; m < 4; ++m)
#pragma unroll
      for (int n = 0; n < 4; ++n)
        acc[m][n] = MFMA16(a[m], b[n], acc[m][n]);
    __syncthreads();
  }

  const int r0 = brow + wr * 64 + lg * 4;
  const int c0 = bcol + wc * 64 + lr;
#pragma unroll
  for (int m = 0; m < 4; ++m)
#pragma unroll
    for (int n = 0; n < 4; ++n)
#pragma unroll
      for (int r = 0; r < 4; ++r) {
        size_t idx = (size_t)(r0 + m * 16 + r) * N + c0 + n * 16;
        if (EPI == 0)
          Cb[idx] = (__bf16)acc[m][n][r];
        else
          Cf[idx] = acc[m][n][r] + resid[idx];
      }
}

// ---------------- flash attention ----------------
// Qh/Kh/Vh/Ctx layout: [B*S][H*64] bf16, per-head col slice h*64.
// Block: 4 waves x 32 Q-rows = 128 Q-rows; iterate KV in blocks of 64.
__global__ __launch_bounds__(256) void attn_kernel(const __bf16* __restrict__ Qh,
                                                   const __bf16* __restrict__ Kh,
                                                   const __bf16* __restrict__ Vh,
                                                   __bf16* __restrict__ Ctx) {
  __shared__ __bf16 Vt[64 * 64];       // [vd][kv]
  __shared__ __bf16 Pl[4][32 * 64];    // per-wave P tile [q][kv]
  const int t = threadIdx.x, l = t & 63, w = t >> 6;
  const int lr = l & 15, lg = l >> 4;
  const int bh = blockIdx.y;
  const size_t base = (size_t)(bh >> 4) * (2048 * 1024) + (size_t)(bh & 15) * 64;
  const int q0 = blockIdx.x * 128 + w * 32;

  bf16x8 aq[2][2];
#pragma unroll
  for (int m = 0; m < 2; ++m)
#pragma unroll
    for (int kc = 0; kc < 2; ++kc)
      aq[m][kc] = *(const bf16x8*)(Qh + base + (size_t)(q0 + m * 16 + lr) * 1024 + kc * 32 + lg * 8);

  f32x4 o[2][4] = {};
  float rm[2][4], rl[2][4];
#pragma unroll
  for (int m = 0; m < 2; ++m)
#pragma unroll
    for (int r = 0; r < 4; ++r) { rm[m][r] = -1e30f; rl[m][r] = 0.f; }

  const int vkr = t >> 2, vc0 = (t & 3) * 16;
  const __bf16* Vg = Vh + base + (size_t)vkr * 1024 + vc0;

  for (int kv0 = 0; kv0 < 2048; kv0 += 64) {
    // stage V-tile transposed into LDS
    bf16x8 v0 = *(const bf16x8*)(Vg + (size_t)kv0 * 1024);
    bf16x8 v1 = *(const bf16x8*)(Vg + (size_t)kv0 * 1024 + 8);
#pragma unroll
    for (int j = 0; j < 8; ++j) Vt[(vc0 + j) * 64 + vkr] = v0[j];
#pragma unroll
    for (int j = 0; j < 8; ++j) Vt[(vc0 + 8 + j) * 64 + vkr] = v1[j];
    __syncthreads();

    // S = (Q @ K^T) * 1/sqrt(64)
    f32x4 s[2][4];
#pragma unroll
    for (int n = 0; n < 4; ++n) {
      const __bf16* krow = Kh + base + (size_t)(kv0 + n * 16 + lr) * 1024 + lg * 8;
      bf16x8 bk0 = *(const bf16x8*)(krow);
      bf16x8 bk1 = *(const bf16x8*)(krow + 32);
#pragma unroll
      for (int m = 0; m < 2; ++m) {
        f32x4 acc = {};
        acc = MFMA16(aq[m][0], bk0, acc);
        acc = MFMA16(aq[m][1], bk1, acc);
        s[m][n] = acc * 0.125f;
      }
    }

    // online softmax (rows live in C-layout: row = m*16 + lg*4 + r, col spread over n,lr)
#pragma unroll
    for (int m = 0; m < 2; ++m) {
      float tmax[4], corr[4], ts[4];
#pragma unroll
      for (int r = 0; r < 4; ++r)
        tmax[r] = fmaxf(fmaxf(s[m][0][r], s[m][1][r]), fmaxf(s[m][2][r], s[m][3][r]));
#pragma unroll
      for (int mask = 1; mask < 16; mask <<= 1)
#pragma unroll
        for (int r = 0; r < 4; ++r)
          tmax[r] = fmaxf(tmax[r], __shfl_xor(tmax[r], mask));
#pragma unroll
      for (int r = 0; r < 4; ++r) {
        float nm = fmaxf(rm[m][r], tmax[r]);
        corr[r] = __expf(rm[m][r] - nm);
        rm[m][r] = nm;
      }
#pragma unroll
      for (int n = 0; n < 4; ++n)
#pragma unroll
        for (int r = 0; r < 4; ++r)
          s[m][n][r] = __expf(s[m][n][r] - rm[m][r]);
#pragma unroll
      for (int r = 0; r < 4; ++r)
        ts[r] = s[m][0][r] + s[m][1][r] + s[m][2][r] + s[m][3][r];
#pragma unroll
      for (int mask = 1; mask < 16; mask <<= 1)
#pragma unroll
        for (int r = 0; r < 4; ++r)
          ts[r] += __shfl_xor(ts[r], mask);
#pragma unroll
      for (int r = 0; r < 4; ++r)
        rl[m][r] = rl[m][r] * corr[r] + ts[r];
#pragma unroll
      for (int n = 0; n < 4; ++n)
#pragma unroll
        for (int r = 0; r < 4; ++r)
          o[m][n][r] *= corr[r];
      // stash P (bf16) in per-wave LDS via the verified C/D layout
#pragma unroll
      for (int n = 0; n < 4; ++n)
#pragma unroll
        for (int r = 0; r < 4; ++r)
          Pl[w][(m * 16 + lg * 4 + r) * 64 + n * 16 + lr] = (__bf16)s[m][n][r];
    }

    // PV: o += P @ V
    bf16x8 bv[4][2];
#pragma unroll
    for (int n = 0; n < 4; ++n)
#pragma unroll
      for (int kc = 0; kc < 2; ++kc)
        bv[n][kc] = *(const bf16x8*)(Vt + (n * 16 + lr) * 64 + kc * 32 + lg * 8);
#pragma unroll
    for (int m = 0; m < 2; ++m) {
      bf16x8 pa0 = *(const bf16x8*)(&Pl[w][(m * 16 + lr) * 64 + lg * 8]);
      bf16x8 pa1 = *(const bf16x8*)(&Pl[w][(m * 16 + lr) * 64 + 32 + lg * 8]);
#pragma unroll
      for (int n = 0; n < 4; ++n) {
        o[m][n] = MFMA16(pa0, bv[n][0], o[m][n]);
        o[m][n] = MFMA16(pa1, bv[n][1], o[m][n]);
      }
    }
    __syncthreads();
  }

#pragma unroll
  for (int m = 0; m < 2; ++m)
#pragma unroll
    for (int n = 0; n < 4; ++n)
#pragma unroll
      for (int r = 0; r < 4; ++r)
        Ctx[base + (size_t)(q0 + m * 16 + lg * 4 + r) * 1024 + n * 16 + lr] =
            (__bf16)(o[m][n][r] / rl[m][r]);
}

// ---------------- LayerNorm over D=1024 (fp32) ----------------
__global__ __launch_bounds__(256) void ln_kernel(const float* __restrict__ x,
                                                 const float* __restrict__ g,
                                                 const float* __restrict__ bta,
                                                 float* __restrict__ out) {
  __shared__ float sred[4], s2red[4];
  const int row = blockIdx.x, t = threadIdx.x;
  float4 v = ((const float4*)(x + (size_t)row * 1024))[t];
  float s = v.x + v.y + v.z + v.w;
  float s2 = v.x * v.x + v.y * v.y + v.z * v.z + v.w * v.w;
#pragma unroll
  for (int mask = 1; mask < 64; mask <<= 1) {
    s += __shfl_xor(s, mask);
    s2 += __shfl_xor(s2, mask);
  }
  if ((t & 63) == 0) { sred[t >> 6] = s; s2red[t >> 6] = s2; }
  __syncthreads();
  s = sred[0] + sred[1] + sred[2] + sred[3];
  s2 = s2red[0] + s2red[1] + s2red[2] + s2red[3];
  float mu = s * (1.f / 1024.f);
  float inv = rsqrtf(s2 * (1.f / 1024.f) - mu * mu + 1e-6f);
  float4 gv = ((const float4*)g)[t];
  float4 bv = ((const float4*)bta)[t];
  float4 ov;
  ov.x = (v.x - mu) * inv * gv.x + bv.x;
  ov.y = (v.y - mu) * inv * gv.y + bv.y;
  ov.z = (v.z - mu) * inv * gv.z + bv.z;
  ov.w = (v.w - mu) * inv * gv.w + bv.w;
  ((float4*)(out + (size_t)row * 1024))[t] = ov;
}

extern "C" void kernel_launch(void* const* d_in, const int* in_sizes, int n_in,
                              void* d_out, int out_size, void* d_ws, size_t ws_size,
                              hipStream_t stream) {
  const float* q  = (const float*)d_in[0];
  const float* k  = (const float*)d_in[1];
  const float* v  = (const float*)d_in[2];
  const float* Wq = (const float*)d_in[3];
  const float* Wk = (const float*)d_in[4];
  const float* Wv = (const float*)d_in[5];
  const float* Wo = (const float*)d_in[6];
  const float* g  = (const float*)d_in[7];
  const float* bt = (const float*)d_in[8];
  float* out = (float*)d_out;

  const int NTOK = 4 * 2048;        // 8192 rows
  const int NEL = NTOK * 1024;      // 8388608 elements

  // workspace layout (bf16 unless noted); ~109 MB total with reuse
  __bf16* qb  = (__bf16*)d_ws;
  __bf16* kb  = qb + NEL;
  __bf16* vb  = kb + NEL;
  __bf16* WqT = vb + NEL;
  __bf16* WkT = WqT + 1024 * 1024;
  __bf16* WvT = WkT + 1024 * 1024;
  __bf16* WoT = WvT + 1024 * 1024;
  __bf16* Qh  = WoT + 1024 * 1024;
  __bf16* Kh  = Qh + NEL;
  __bf16* Vh  = Kh + NEL;
  __bf16* ctx = qb;              // reuse: qb dead after Qh GEMM
  float*  ao  = (float*)kb;      // reuse: kb+vb dead after Kh/Vh GEMMs (33.5MB)

  cvt_kernel<<<NEL / 1024, 256, 0, stream>>>(q, qb, NEL / 4);
  cvt_kernel<<<NEL / 1024, 256, 0, stream>>>(k, kb, NEL / 4);
  cvt_kernel<<<NEL / 1024, 256, 0, stream>>>(v, vb, NEL / 4);

  dim3 wtb(64, 4), wtg(16, 16);
  wtrans_kernel<<<wtg, wtb, 0, stream>>>(Wq, WqT);
  wtrans_kernel<<<wtg, wtb, 0, stream>>>(Wk, WkT);
  wtrans_kernel<<<wtg, wtb, 0, stream>>>(Wv, WvT);
  wtrans_kernel<<<wtg, wtb, 0, stream>>>(Wo, WoT);

  dim3 gg(1024 / 128, NTOK / 128);
  gemm128_kernel<0><<<gg, 256, 0, stream>>>(qb, WqT, Qh, nullptr, nullptr, NTOK, 1024, 1024);
  gemm128_kernel<0><<<gg, 256, 0, stream>>>(kb, WkT, Kh, nullptr, nullptr, NTOK, 1024, 1024);
  gemm128_kernel<0><<<gg, 256, 0, stream>>>(vb, WvT, Vh, nullptr, nullptr, NTOK, 1024, 1024);

  attn_kernel<<<dim3(2048 / 128, 64), 256, 0, stream>>>(Qh, Kh, Vh, ctx);

  gemm128_kernel<1><<<gg, 256, 0, stream>>>(ctx, WoT, nullptr, ao, q, NTOK, 1024, 1024);

  ln_kernel<<<NTOK, 256, 0, stream>>>(ao, g, bt, out);
}

// Round 3
// 515.816 us; speedup vs baseline: 1.2986x; 1.2986x over previous
//
#include <hip/hip_runtime.h>

typedef __bf16 bf16x8 __attribute__((ext_vector_type(8)));
typedef __bf16 bf16x4 __attribute__((ext_vector_type(4)));
typedef float  f32x4  __attribute__((ext_vector_type(4)));

#define MFMA16(a, b, c) __builtin_amdgcn_mfma_f32_16x16x32_bf16(a, b, c, 0, 0, 0)
#define AS1(p) ((__attribute__((address_space(1))) void*)(p))
#define AS3(p) ((__attribute__((address_space(3))) void*)(p))

union U8 { uint u[4]; bf16x8 v; };
union U4 { bf16x4 h[2]; bf16x8 v; };

__device__ inline uint packbf(float a, float b) {
  union { __bf16 h[2]; uint u; } x;
  x.h[0] = (__bf16)a; x.h[1] = (__bf16)b; return x.u;
}

// ---------------- fp32 -> bf16 convert (vectorized) ----------------
__global__ __launch_bounds__(256) void cvt_kernel(const float* __restrict__ in,
                                                  __bf16* __restrict__ out, int n4) {
  int i = blockIdx.x * blockDim.x + threadIdx.x;
  if (i < n4) {
    float4 v = ((const float4*)in)[i];
    bf16x4 o = {(__bf16)v.x, (__bf16)v.y, (__bf16)v.z, (__bf16)v.w};
    *(bf16x4*)(out + (size_t)i * 4) = o;
  }
}

// ---------------- weight transpose+convert: fp32 [1024][1024] -> bf16 [N][K] ----
__global__ void wtrans_kernel(const float* __restrict__ in, __bf16* __restrict__ out) {
  __shared__ __bf16 t[64][65];
  int bx = blockIdx.x * 64, by = blockIdx.y * 64;
  int tx = threadIdx.x;
  for (int ty = threadIdx.y; ty < 64; ty += 4)
    t[ty][tx] = (__bf16)in[(size_t)(by + ty) * 1024 + bx + tx];
  __syncthreads();
  for (int ty = threadIdx.y; ty < 64; ty += 4)
    out[(size_t)(bx + ty) * 1024 + by + tx] = t[tx][ty];
}

// ---------------- bf16 GEMM: C[M,N] = A[M,K] @ BT[N,K]^T ----------------
// MODE 0: bf16 C.  MODE 1: fp32 C + fp32 residual.  MODE 2: bf16 C * 0.125.
// MODE 3: bf16 transposed per-head store -> VhT[(b*16+h)*64 + d][2048] (s-major).
template <int MODE>
__global__ __launch_bounds__(256) void gemm128_kernel(
    const __bf16* __restrict__ A, const __bf16* __restrict__ BT,
    __bf16* __restrict__ Cb, float* __restrict__ Cf,
    const float* __restrict__ resid, int M, int N, int K) {
  __shared__ __bf16 As[128 * 32];
  __shared__ __bf16 Bs[128 * 32];
  const int t = threadIdx.x, l = t & 63, w = t >> 6;
  const int lr = l & 15, lg = l >> 4;
  const int brow = blockIdx.y * 128, bcol = blockIdx.x * 128;
  const int wr = w >> 1, wc = w & 1;
  f32x4 acc[4][4] = {};

  const int srow = w * 16 + (l >> 2);
  const int scol = (l & 3) * 8;
  const __bf16* Ag = A + (size_t)(brow + srow) * K + scol;
  const __bf16* Bg = BT + (size_t)(bcol + srow) * K + scol;
  __bf16* Asw = As + w * 512;
  __bf16* Bsw = Bs + w * 512;

  for (int k0 = 0; k0 < K; k0 += 32) {
    __builtin_amdgcn_global_load_lds(AS1(Ag + k0), AS3(Asw), 16, 0, 0);
    __builtin_amdgcn_global_load_lds(AS1(Ag + k0 + (size_t)64 * K), AS3(Asw + 2048), 16, 0, 0);
    __builtin_amdgcn_global_load_lds(AS1(Bg + k0), AS3(Bsw), 16, 0, 0);
    __builtin_amdgcn_global_load_lds(AS1(Bg + k0 + (size_t)64 * K), AS3(Bsw + 2048), 16, 0, 0);
    __syncthreads();
    bf16x8 a[4], b[4];
#pragma unroll
    for (int m = 0; m < 4; ++m)
      a[m] = *(const bf16x8*)(As + (wr * 64 + m * 16 + lr) * 32 + lg * 8);
#pragma unroll
    for (int n = 0; n < 4; ++n)
      b[n] = *(const bf16x8*)(Bs + (wc * 64 + n * 16 + lr) * 32 + lg * 8);
#pragma unroll
    for (int m = 0; m < 4; ++m)
#pragma unroll
      for (int n = 0; n < 4; ++n)
        acc[m][n] = MFMA16(a[m], b[n], acc[m][n]);
    __syncthreads();
  }

  const int r0 = brow + wr * 64 + lg * 4;
  const int c0 = bcol + wc * 64 + lr;
#pragma unroll
  for (int m = 0; m < 4; ++m)
#pragma unroll
    for (int n = 0; n < 4; ++n) {
      if (MODE == 3) {
        const int dg = c0 + n * 16;
        const int tok = r0 + m * 16;
        bf16x4 pk4;
#pragma unroll
        for (int r = 0; r < 4; ++r) pk4[r] = (__bf16)acc[m][n][r];
        size_t idx = ((size_t)((tok >> 11) * 16 + (dg >> 6)) * 64 + (dg & 63)) * 2048 + (tok & 2047);
        *(bf16x4*)(Cb + idx) = pk4;
      } else {
#pragma unroll
        for (int r = 0; r < 4; ++r) {
          size_t idx = (size_t)(r0 + m * 16 + r) * N + c0 + n * 16;
          if (MODE == 0) Cb[idx] = (__bf16)acc[m][n][r];
          if (MODE == 2) Cb[idx] = (__bf16)(acc[m][n][r] * 0.125f);
          if (MODE == 1) Cf[idx] = acc[m][n][r] + resid[idx];
        }
      }
    }
}

// ---------------- flash attention (swapped QK^T, zero-shuffle PV) ----------------
// Qh/Kh/Ctx: [B*S][H*64] bf16 (Qh pre-scaled by 1/8). VhT: [(b*16+h)*64+d][2048] bf16.
// Block: 4 waves x 32 Q-rows = 128 Q-rows; KV blocks of 64, double-buffered V in LDS.
__global__ __launch_bounds__(256) void attn_kernel(const __bf16* __restrict__ Qh,
                                                   const __bf16* __restrict__ Kh,
                                                   const __bf16* __restrict__ VhT,
                                                   __bf16* __restrict__ Ctx) {
  __shared__ __bf16 Vbuf[2 * 4096];  // two 64x64 tiles, XOR-swizzled rows of 128B
  const int t = threadIdx.x, l = t & 63, w = t >> 6;
  const int lr = l & 15, lg = l >> 4;
  const int bh = blockIdx.y;
  const size_t base = (size_t)(bh >> 4) * (2048 * 1024) + (size_t)(bh & 15) * 64;
  const int q0 = blockIdx.x * 128 + w * 32;

  // Q fragments (B-operand for S^T): Q[q0+nq*16+lr][kc*32+lg*8+j]
  bf16x8 aq[2][2];
#pragma unroll
  for (int nq = 0; nq < 2; ++nq)
#pragma unroll
    for (int kc = 0; kc < 2; ++kc)
      aq[nq][kc] = *(const bf16x8*)(Qh + base + (size_t)(q0 + nq * 16 + lr) * 1024 + kc * 32 + lg * 8);

  // O^T accumulator: o[md][nq], rows d=md*16+lg*4+r, col q=nq*16+lr
  f32x4 o[4][2] = {};
  float rm[2] = {-1e30f, -1e30f}, rl[2] = {0.f, 0.f};

  // V staging: per-lane pre-swizzled global source (inverse of read XOR-swizzle)
  const int l8 = l & 7, lrow = l >> 3;
  const __bf16* vsrc = VhT + (size_t)bh * 131072 + (size_t)(w * 16 + lrow) * 2048 + ((l8 ^ lrow) * 8);

  // LDS read offsets (bytes), lane-constant: row lr stride 128B, col XOR (lr&7)<<4
  const int xorm = (l8) << 4;
  int vo[2][2];
#pragma unroll
  for (int kc = 0; kc < 2; ++kc)
#pragma unroll
    for (int h = 0; h < 2; ++h)
      vo[kc][h] = lr * 128 + ((kc * 64 + h * 32 + lg * 8) ^ xorm);

  // prologue: stage tile 0
  {
    __bf16* d0 = Vbuf + w * 1024;
    __builtin_amdgcn_global_load_lds(AS1(vsrc), AS3(d0), 16, 0, 0);
    __builtin_amdgcn_global_load_lds(AS1(vsrc + 16384), AS3(d0 + 512), 16, 0, 0);
  }
  __syncthreads();

  for (int tt = 0; tt < 32; ++tt) {
    const __bf16* Vb = Vbuf + (tt & 1) * 4096;
    __bf16* Vn = Vbuf + ((tt + 1) & 1) * 4096;
    const int kv0 = tt * 64;
    const int kvn = ((tt + 1) & 31) * 64;

    // stage next V tile (lands before next iteration's barrier exit)
    __builtin_amdgcn_global_load_lds(AS1(vsrc + kvn), AS3(Vn + w * 1024), 16, 0, 0);
    __builtin_amdgcn_global_load_lds(AS1(vsrc + kvn + 16384), AS3(Vn + w * 1024 + 512), 16, 0, 0);

    // K fragments (A-operand): K[kv0+mkv*16+lr][kc*32+lg*8+j]
    bf16x8 kf[4][2];
#pragma unroll
    for (int mkv = 0; mkv < 4; ++mkv)
#pragma unroll
      for (int kc = 0; kc < 2; ++kc)
        kf[mkv][kc] = *(const bf16x8*)(Kh + base + (size_t)(kv0 + mkv * 16 + lr) * 1024 + kc * 32 + lg * 8);

    // S^T = K @ Q^T : lane holds S[q=nq*16+lr][kv=mkv*16+lg*4+r]
    f32x4 s[2][4];
    __builtin_amdgcn_s_setprio(1);
#pragma unroll
    for (int nq = 0; nq < 2; ++nq)
#pragma unroll
      for (int mkv = 0; mkv < 4; ++mkv) {
        f32x4 acc = {};
        acc = MFMA16(kf[mkv][0], aq[nq][0], acc);
        acc = MFMA16(kf[mkv][1], aq[nq][1], acc);
        s[nq][mkv] = acc;
      }
    __builtin_amdgcn_s_setprio(0);

    // online softmax, q = nq*16+lr per lane; P packed in-register (zero-shuffle)
    uint pk[2][4][2];
#pragma unroll
    for (int nq = 0; nq < 2; ++nq) {
      float mx = s[nq][0][0];
#pragma unroll
      for (int mkv = 0; mkv < 4; ++mkv)
#pragma unroll
        for (int r = 0; r < 4; ++r) mx = fmaxf(mx, s[nq][mkv][r]);
      mx = fmaxf(mx, __shfl_xor(mx, 16));
      mx = fmaxf(mx, __shfl_xor(mx, 32));
      float nm = fmaxf(rm[nq], mx);
      float corr = __expf(rm[nq] - nm);
      rm[nq] = nm;
      float sum = 0.f;
#pragma unroll
      for (int mkv = 0; mkv < 4; ++mkv) {
        float p0 = __expf(s[nq][mkv][0] - nm);
        float p1 = __expf(s[nq][mkv][1] - nm);
        float p2 = __expf(s[nq][mkv][2] - nm);
        float p3 = __expf(s[nq][mkv][3] - nm);
        sum += (p0 + p1) + (p2 + p3);
        pk[nq][mkv][0] = packbf(p0, p1);
        pk[nq][mkv][1] = packbf(p2, p3);
      }
      sum += __shfl_xor(sum, 16);
      sum += __shfl_xor(sum, 32);
      rl[nq] = rl[nq] * corr + sum;
#pragma unroll
      for (int md = 0; md < 4; ++md) o[md][nq] *= corr;
    }

    // PV: O^T += V^T @ P^T  (k-slot permutation makes P^T frag lane-local)
    __builtin_amdgcn_s_setprio(1);
#pragma unroll
    for (int md = 0; md < 4; ++md) {
#pragma unroll
      for (int kc = 0; kc < 2; ++kc) {
        U4 vf;
        vf.h[0] = *(const bf16x4*)((const char*)Vb + md * 2048 + vo[kc][0]);
        vf.h[1] = *(const bf16x4*)((const char*)Vb + md * 2048 + vo[kc][1]);
#pragma unroll
        for (int nq = 0; nq < 2; ++nq) {
          U8 pf;
          pf.u[0] = pk[nq][2 * kc][0];
          pf.u[1] = pk[nq][2 * kc][1];
          pf.u[2] = pk[nq][2 * kc + 1][0];
          pf.u[3] = pk[nq][2 * kc + 1][1];
          o[md][nq] = MFMA16(vf.v, pf.v, o[md][nq]);
        }
      }
    }
    __builtin_amdgcn_s_setprio(0);

    __syncthreads();  // drains own staging loads; all waves done reading Vb
  }

  // epilogue: O[q][d] = O^T[d][q] / l ; per (md,nq) a contiguous bf16x4 over d
  float rinv[2] = {1.f / rl[0], 1.f / rl[1]};
#pragma unroll
  for (int md = 0; md < 4; ++md)
#pragma unroll
    for (int nq = 0; nq < 2; ++nq) {
      bf16x4 pk4;
#pragma unroll
      for (int r = 0; r < 4; ++r) pk4[r] = (__bf16)(o[md][nq][r] * rinv[nq]);
      *(bf16x4*)(Ctx + base + (size_t)(q0 + nq * 16 + lr) * 1024 + md * 16 + lg * 4) = pk4;
    }
}

// ---------------- LayerNorm over D=1024 (fp32) ----------------
__global__ __launch_bounds__(256) void ln_kernel(const float* __restrict__ x,
                                                 const float* __restrict__ g,
                                                 const float* __restrict__ bta,
                                                 float* __restrict__ out) {
  __shared__ float sred[4], s2red[4];
  const int row = blockIdx.x, t = threadIdx.x;
  float4 v = ((const float4*)(x + (size_t)row * 1024))[t];
  float s = v.x + v.y + v.z + v.w;
  float s2 = v.x * v.x + v.y * v.y + v.z * v.z + v.w * v.w;
#pragma unroll
  for (int mask = 1; mask < 64; mask <<= 1) {
    s += __shfl_xor(s, mask);
    s2 += __shfl_xor(s2, mask);
  }
  if ((t & 63) == 0) { sred[t >> 6] = s; s2red[t >> 6] = s2; }
  __syncthreads();
  s = sred[0] + sred[1] + sred[2] + sred[3];
  s2 = s2red[0] + s2red[1] + s2red[2] + s2red[3];
  float mu = s * (1.f / 1024.f);
  float inv = rsqrtf(s2 * (1.f / 1024.f) - mu * mu + 1e-6f);
  float4 gv = ((const float4*)g)[t];
  float4 bv = ((const float4*)bta)[t];
  float4 ov;
  ov.x = (v.x - mu) * inv * gv.x + bv.x;
  ov.y = (v.y - mu) * inv * gv.y + bv.y;
  ov.z = (v.z - mu) * inv * gv.z + bv.z;
  ov.w = (v.w - mu) * inv * gv.w + bv.w;
  ((float4*)(out + (size_t)row * 1024))[t] = ov;
}

extern "C" void kernel_launch(void* const* d_in, const int* in_sizes, int n_in,
                              void* d_out, int out_size, void* d_ws, size_t ws_size,
                              hipStream_t stream) {
  const float* q  = (const float*)d_in[0];
  const float* k  = (const float*)d_in[1];
  const float* v  = (const float*)d_in[2];
  const float* Wq = (const float*)d_in[3];
  const float* Wk = (const float*)d_in[4];
  const float* Wv = (const float*)d_in[5];
  const float* Wo = (const float*)d_in[6];
  const float* g  = (const float*)d_in[7];
  const float* bt = (const float*)d_in[8];
  float* out = (float*)d_out;

  const int NTOK = 4 * 2048;
  const int NEL = NTOK * 1024;

  __bf16* qb  = (__bf16*)d_ws;
  __bf16* kb  = qb + NEL;
  __bf16* vb  = kb + NEL;
  __bf16* WqT = vb + NEL;
  __bf16* WkT = WqT + 1024 * 1024;
  __bf16* WvT = WkT + 1024 * 1024;
  __bf16* WoT = WvT + 1024 * 1024;
  __bf16* Qh  = WoT + 1024 * 1024;
  __bf16* Kh  = Qh + NEL;
  __bf16* VhT = Kh + NEL;
  __bf16* ctx = qb;
  float*  ao  = (float*)kb;

  cvt_kernel<<<NEL / 1024, 256, 0, stream>>>(q, qb, NEL / 4);
  cvt_kernel<<<NEL / 1024, 256, 0, stream>>>(k, kb, NEL / 4);
  cvt_kernel<<<NEL / 1024, 256, 0, stream>>>(v, vb, NEL / 4);

  dim3 wtb(64, 4), wtg(16, 16);
  wtrans_kernel<<<wtg, wtb, 0, stream>>>(Wq, WqT);
  wtrans_kernel<<<wtg, wtb, 0, stream>>>(Wk, WkT);
  wtrans_kernel<<<wtg, wtb, 0, stream>>>(Wv, WvT);
  wtrans_kernel<<<wtg, wtb, 0, stream>>>(Wo, WoT);

  dim3 gg(1024 / 128, NTOK / 128);
  gemm128_kernel<2><<<gg, 256, 0, stream>>>(qb, WqT, Qh, nullptr, nullptr, NTOK, 1024, 1024);
  gemm128_kernel<0><<<gg, 256, 0, stream>>>(kb, WkT, Kh, nullptr, nullptr, NTOK, 1024, 1024);
  gemm128_kernel<3><<<gg, 256, 0, stream>>>(vb, WvT, VhT, nullptr, nullptr, NTOK, 1024, 1024);

  attn_kernel<<<dim3(2048 / 128, 64), 256, 0, stream>>>(Qh, Kh, VhT, ctx);

  gemm128_kernel<1><<<gg, 256, 0, stream>>>(ctx, WoT, nullptr, ao, q, NTOK, 1024, 1024);

  ln_kernel<<<NTOK, 256, 0, stream>>>(ao, g, bt, out);
}